// Round 2
// baseline (348.521 us; speedup 1.0000x reference)
//
#include <hip/hip_runtime.h>

// ---------------------------------------------------------------------------
// Earth padding of 5 strips (B=1, C=256) + edge-row cross-strip convs.
// Outputs (concatenated): (256,34,364)(256,64,724)(256,184,1444)(256,64,724)(256,34,364)
//
// Round-2 structure: one tiny weight-transpose kernel, then ONE mega kernel:
//   blocks [0,1080)        : 8 edge-conv jobs (VALU-bound)   -- dispatched first
//   blocks [1080,93240)    : pad-copies of the 5 strips (HBM-bound)
//   blocks [93240,93604)   : zero rows of strip0/strip4
// Disjoint write sets -> no ordering needed; conv overlaps copy BW.
// ---------------------------------------------------------------------------

struct ConvJob {
  const float* x; const float* wt; const float* bias; float* out;
  int Hin, Win, r0, Hout, Wcore, h0, type, blk_start;
  // type 0: circular transposed conv (stride-2 up),  tile = 16 m, 2 blocks/row-pair unit
  // type 1: circular forward conv (stride-2 down),   tile = 8 u
};

struct MegaParams {
  ConvJob j[8];
  const float* in0; const float* in1; const float* in2; const float* in3; const float* in4;
  float* o0; float* o1; float* o2; float* o3; float* o4;
};

struct WTParams { const float* src[4]; float* dst[4]; };

// --- fused weight transpose: dst[(ic*5+k)*256 + oc] for all 4 weight tensors ---
// which 0,1: src is wi [ic][oc][1][k] ; which 2,3: src is wo [oc][ic][1][k]
__global__ __launch_bounds__(256) void transpose_all_kernel(WTParams p) {
  int b = blockIdx.x;                       // 5120 blocks = 4 * 1280
  int which = b / 1280;
  int idx = (b - which * 1280) * 256 + threadIdx.x;
  int oc = idx & 255;
  int q = idx >> 8;
  int k = q % 5;
  int ic = q / 5;
  const float* s = p.src[which];
  float v = (which < 2) ? s[(ic * 256 + oc) * 5 + k] : s[(oc * 256 + ic) * 5 + k];
  p.dst[which][idx] = v;
}

// --- interior pad-copy rows 2..H+1, circular width pad; compile-time H,W ---
template <int H, int W>
__device__ __forceinline__ void copy_strip(const float* __restrict__ in,
                                           float* __restrict__ out, int id) {
  constexpr int WO4 = W / 4 + 1;            // (W+4)/4
  int w4 = id % WO4;
  int hz = id / WO4;
  int h = hz % H;
  int c = hz / H;
  const float* src = in + ((size_t)(c * H + h)) * W;
  int wc = w4 * 4;
  float4 v;
  if (w4 >= 1 && wc <= W - 4) {
    float2 a = *(const float2*)(src + wc - 2);
    float2 b = *(const float2*)(src + wc);
    v = make_float4(a.x, a.y, b.x, b.y);
  } else {
    int c0 = wc - 2 + W;
    v.x = src[c0 % W];
    v.y = src[(c0 + 1) % W];
    v.z = src[(c0 + 2) % W];
    v.w = src[(c0 + 3) % W];
  }
  *(float4*)(out + ((size_t)(c * (H + 4) + h + 2)) * (W + 4) + wc) = v;
}

// --- one conv block: thread = oc, LDS-staged X columns, streaming-x inner loop ---
__device__ __forceinline__ void conv_block(const ConvJob jb, int local, int t, float* xs) {
  int tile = local >> 1;
  int r = local & 1;
  const int Win = jb.Win;
  const float* xrow = jb.x + ((size_t)(t * jb.Hin + jb.r0 + r)) * Win;
  const float* wt = jb.wt + t;
  const int Wop = jb.Wcore + 4;
  float* orow = jb.out + ((size_t)(t * jb.Hout + jb.h0 + r)) * Wop;

  if (jb.type == 1) {
    // forward: out[u] = b + sum_ic sum_k w[k] * x[(2u+k-2) mod Win], tile of 8 u
    int u0 = tile * 8;
    int cb = 2 * u0 - 2;
#pragma unroll
    for (int cc = 0; cc < 19; ++cc) {
      int col = cb + cc;
      col += (col < 0) ? Win : 0;
      col -= (col >= Win) ? Win : 0;
      xs[cc * 256 + t] = xrow[col];
    }
    __syncthreads();
    float bv = jb.bias[t];
    float acc[8];
#pragma unroll
    for (int i = 0; i < 8; ++i) acc[i] = bv;
    for (int ic0 = 0; ic0 < 256; ic0 += 4) {
      float w[4][5];
#pragma unroll
      for (int i = 0; i < 4; ++i)
#pragma unroll
        for (int k = 0; k < 5; ++k) w[i][k] = wt[((ic0 + i) * 5 + k) * 256];
#pragma unroll
      for (int cc = 0; cc < 19; ++cc) {
        float4 xq = *(const float4*)&xs[cc * 256 + ic0];
#pragma unroll
        for (int i = 0; i < 8; ++i) {
          int k = cc - 2 * i;                 // column cc serves out i with tap k
          if (k >= 0 && k < 5)
            acc[i] += w[0][k] * xq.x + w[1][k] * xq.y + w[2][k] * xq.z + w[3][k] * xq.w;
        }
      }
    }
#pragma unroll
    for (int i = 0; i < 8; ++i) {
      int g = u0 + i;
      float vv = acc[i];
      orow[2 + g] = vv;
      if (g < 2) orow[jb.Wcore + 2 + g] = vv;
      if (g >= jb.Wcore - 2) orow[g - (jb.Wcore - 2)] = vv;
    }
  } else {
    // transposed: out[m] = sum_ic sum_{k == m mod 2} w[k] * x[((m+2-k)/2) mod Win], tile of 16 m
    int m0 = tile * 16;
    int j0 = (m0 >> 1) - 1;
#pragma unroll
    for (int cc = 0; cc < 10; ++cc) {
      int col = j0 + cc;
      col += (col < 0) ? Win : 0;
      col -= (col >= Win) ? Win : 0;
      xs[cc * 256 + t] = xrow[col];
    }
    __syncthreads();
    float acc[16];
#pragma unroll
    for (int i = 0; i < 16; ++i) acc[i] = 0.f;
    for (int ic0 = 0; ic0 < 256; ic0 += 4) {
      float w[4][5];
#pragma unroll
      for (int i = 0; i < 4; ++i)
#pragma unroll
        for (int k = 0; k < 5; ++k) w[i][k] = wt[((ic0 + i) * 5 + k) * 256];
#pragma unroll
      for (int cc = 0; cc < 10; ++cc) {
        float4 xq = *(const float4*)&xs[cc * 256 + ic0];
#pragma unroll
        for (int ml = 0; ml < 16; ++ml) {
          int k = ml + 4 - 2 * cc;            // column cc serves out ml with tap k
          if (k >= 0 && k < 5)
            acc[ml] += w[0][k] * xq.x + w[1][k] * xq.y + w[2][k] * xq.z + w[3][k] * xq.w;
        }
      }
    }
#pragma unroll
    for (int i = 0; i < 16; ++i) {
      int g = m0 + i;
      float vv = acc[i];
      orow[2 + g] = vv;
      if (g < 2) orow[jb.Wcore + 2 + g] = vv;
      if (g >= jb.Wcore - 2) orow[g - (jb.Wcore - 2)] = vv;
    }
  }
}

// --- the mega kernel: conv (first) + copies + zero rows in one dispatch ---
__global__ __launch_bounds__(256) void mega_kernel(MegaParams p) {
  __shared__ float xs[19 * 256];            // 19.5 KB -> 8 blocks/CU (= max threads) anyway
  int bx = blockIdx.x;
  int t = threadIdx.x;
  if (bx < 1080) {
    int ji = 0;
#pragma unroll
    for (int i = 1; i < 8; ++i)
      if (bx >= p.j[i].blk_start) ji = i;
    conv_block(p.j[ji], bx - p.j[ji].blk_start, t, xs);
  } else if (bx < 3810) {
    copy_strip<30, 360>(p.in0, p.o0, (bx - 1080) * 256 + t);
  } else if (bx < 14670) {
    copy_strip<60, 720>(p.in1, p.o1, (bx - 3810) * 256 + t);
  } else if (bx < 79650) {
    copy_strip<180, 1440>(p.in2, p.o2, (bx - 14670) * 256 + t);
  } else if (bx < 90510) {
    copy_strip<60, 720>(p.in3, p.o3, (bx - 79650) * 256 + t);
  } else if (bx < 93240) {
    copy_strip<30, 360>(p.in4, p.o4, (bx - 90510) * 256 + t);
  } else {
    // zero rows: strip0 rows 0,1 ; strip4 rows 32,33  (364 blocks exactly)
    int id = (bx - 93240) * 256 + t;
    int w4 = id % 91;
    int t2 = id / 91;                       // 0..1023
    int strip = t2 >> 9;
    int cr = t2 & 511;
    int c = cr >> 1;
    int r = cr & 1;
    float* o = (strip == 0) ? p.o0 + ((size_t)(c * 34 + r)) * 364
                            : p.o4 + ((size_t)(c * 34 + 32 + r)) * 364;
    *(float4*)(o + w4 * 4) = make_float4(0.f, 0.f, 0.f, 0.f);
  }
}

extern "C" void kernel_launch(void* const* d_in, const int* in_sizes, int n_in,
                              void* d_out, int out_size, void* d_ws, size_t ws_size,
                              hipStream_t stream) {
  const float* s0 = (const float*)d_in[0];   // (256,30,360)
  const float* s1 = (const float*)d_in[1];   // (256,60,720)
  const float* s2 = (const float*)d_in[2];   // (256,180,1440)
  const float* s3 = (const float*)d_in[3];   // (256,60,720)
  const float* s4 = (const float*)d_in[4];   // (256,30,360)
  const float* wi0 = (const float*)d_in[5];  // (256,256,1,5) [ic][oc][k]
  const float* wi1 = (const float*)d_in[6];
  const float* wo0 = (const float*)d_in[7];  // (256,256,1,5) [oc][ic][k]
  const float* bo0 = (const float*)d_in[8];
  const float* wo1 = (const float*)d_in[9];
  const float* bo1 = (const float*)d_in[10];

  float* out = (float*)d_out;
  float* out0 = out;                 // (256,34,364)
  float* out1 = out + 3168256;       // (256,64,724)
  float* out2 = out + 15030272;      // (256,184,1444)
  float* out3 = out + 83048448;      // (256,64,724)
  float* out4 = out + 94910464;      // (256,34,364)

  // transposed weights in workspace: [ic][k][oc], 327680 floats each
  float* wt0 = (float*)d_ws;
  float* wt1 = wt0 + 327680;
  float* wt2 = wt1 + 327680;
  float* wt3 = wt2 + 327680;

  WTParams wp;
  wp.src[0] = wi0; wp.src[1] = wi1; wp.src[2] = wo0; wp.src[3] = wo1;
  wp.dst[0] = wt0; wp.dst[1] = wt1; wp.dst[2] = wt2; wp.dst[3] = wt3;
  transpose_all_kernel<<<5120, 256, 0, stream>>>(wp);

  MegaParams mp;
  //           x   wt    bias    out   Hin  Win   r0  Hout Wcore h0  type blk_start
  mp.j[0] = {s1, wt0, nullptr, out2,  60,  720,  58, 184, 1440,   0, 0,   0}; // convT -> out2 top    (180 blk)
  mp.j[1] = {s3, wt0, nullptr, out2,  60,  720,   0, 184, 1440, 182, 0, 180}; // convT -> out2 bottom (180 blk)
  mp.j[2] = {s0, wt1, nullptr, out1,  30,  360,  28,  64,  720,   0, 0, 360}; // convT -> out1 top    ( 90 blk)
  mp.j[3] = {s4, wt1, nullptr, out3,  30,  360,   0,  64,  720,  62, 0, 450}; // convT -> out3 bottom ( 90 blk)
  mp.j[4] = {s2, wt2, bo0,     out1, 180, 1440,   0,  64,  720,  62, 1, 540}; // fwd   -> out1 bottom (180 blk)
  mp.j[5] = {s2, wt2, bo0,     out3, 180, 1440, 178,  64,  720,   0, 1, 720}; // fwd   -> out3 top    (180 blk)
  mp.j[6] = {s1, wt3, bo1,     out0,  60,  720,   0,  34,  360,  32, 1, 900}; // fwd   -> out0 bottom ( 90 blk)
  mp.j[7] = {s3, wt3, bo1,     out4,  60,  720,  58,  34,  360,   0, 1, 990}; // fwd   -> out4 top    ( 90 blk)
  mp.in0 = s0; mp.in1 = s1; mp.in2 = s2; mp.in3 = s3; mp.in4 = s4;
  mp.o0 = out0; mp.o1 = out1; mp.o2 = out2; mp.o3 = out3; mp.o4 = out4;

  mega_kernel<<<93604, 256, 0, stream>>>(mp);
}

// Round 3
// 311.954 us; speedup vs baseline: 1.1172x; 1.1172x over previous
//
#include <hip/hip_runtime.h>

// ---------------------------------------------------------------------------
// Earth padding of 5 strips (B=1, C=256) + edge-row cross-strip convs.
// Outputs (concatenated): (256,34,364)(256,64,724)(256,184,1444)(256,64,724)(256,34,364)
//
// Round-3 structure: tiny weight-transpose kernel, then ONE persistent-block
// mega kernel, grid = 1784 blocks (<= 7 blocks/CU resident everywhere):
//   [0,540)      conv blocks, each runs 2 of the 1080 conv units (VALU-bound)
//   [540,1410)   strip2 row-copies (870 blocks, grid-stride over rows)
//   [1410,1556)  strip1 row-copies (146)
//   [1556,1702)  strip3 row-copies (146)
//   [1702,1740)  strip0 row-copies (38)
//   [1740,1778)  strip4 row-copies (38)
//   [1778,1784)  zero rows of strip0/strip4 (6)
// Disjoint write sets -> no ordering needed; conv overlaps copy bandwidth.
// ---------------------------------------------------------------------------

struct ConvJob {
  const float* x; const float* wt; const float* bias; float* out;
  int Hin, Win, r0, Hout, Wcore, h0, type, blk_start;
};

struct MegaParams {
  ConvJob j[8];
  const float* in0; const float* in1; const float* in2; const float* in3; const float* in4;
  float* o0; float* o1; float* o2; float* o3; float* o4;
};

struct WTParams { const float* src[4]; float* dst[4]; };

// --- fused weight transpose: dst[(ic*5+k)*256 + oc] for all 4 weight tensors ---
// which 0,1: src is wi [ic][oc][1][k] ; which 2,3: src is wo [oc][ic][1][k]
__global__ __launch_bounds__(256) void transpose_all_kernel(WTParams p) {
  int b = blockIdx.x;                       // 5120 blocks = 4 * 1280
  int which = b / 1280;
  int idx = (b - which * 1280) * 256 + threadIdx.x;
  int oc = idx & 255;
  int q = idx >> 8;
  int k = q % 5;
  int ic = q / 5;
  const float* s = p.src[which];
  float v = (which < 2) ? s[(ic * 256 + oc) * 5 + k] : s[(oc * 256 + ic) * 5 + k];
  p.dst[which][idx] = v;
}

// --- row-based pad-copy: wave owns a row; circular width pad via lane-0 tail ---
template <int H, int W>
__device__ __forceinline__ void copy_strip_rows(const float* __restrict__ in,
                                                float* __restrict__ out,
                                                int lb, int nb, int t) {
  constexpr int WO4 = W / 4 + 1;            // (W+4)/4
  constexpr int NROWS = 256 * H;
  int wave = t >> 6, lane = t & 63;
  for (int row = lb * 4 + wave; row < NROWS; row += nb * 4) {
    int c = row / H;                        // constexpr division (magic mul)
    const float* src = in + (size_t)row * W;
    float* dst = out + (size_t)(row + c * 4 + 2) * (W + 4);
    for (int w4 = 1 + lane; w4 < WO4 - 1; w4 += 64) {
      const float* p = src + w4 * 4;
      float2 a = *(const float2*)(p - 2);
      float2 b = *(const float2*)(p);
      *(float4*)(dst + w4 * 4) = make_float4(a.x, a.y, b.x, b.y);
    }
    if (lane == 0) {
      // dst[0..3] == dst[W..W+3] == {x[W-2], x[W-1], x[0], x[1]}
      float2 E = *(const float2*)(src + W - 2);
      float2 F = *(const float2*)(src);
      float4 v = make_float4(E.x, E.y, F.x, F.y);
      *(float4*)(dst) = v;
      *(float4*)(dst + W) = v;
    }
  }
}

// --- one conv unit: thread = oc, LDS-staged X columns, streaming-x inner loop ---
__device__ __forceinline__ void conv_block(const ConvJob jb, int local, int t, float* xs) {
  int tile = local >> 1;
  int r = local & 1;
  const int Win = jb.Win;
  const float* xrow = jb.x + ((size_t)(t * jb.Hin + jb.r0 + r)) * Win;
  const float* wt = jb.wt + t;
  const int Wop = jb.Wcore + 4;
  float* orow = jb.out + ((size_t)(t * jb.Hout + jb.h0 + r)) * Wop;

  if (jb.type == 1) {
    // forward: out[u] = b + sum_ic sum_k w[k] * x[(2u+k-2) mod Win], tile of 8 u
    int u0 = tile * 8;
    int cb = 2 * u0 - 2;
#pragma unroll
    for (int cc = 0; cc < 19; ++cc) {
      int col = cb + cc;
      col += (col < 0) ? Win : 0;
      col -= (col >= Win) ? Win : 0;
      xs[cc * 256 + t] = xrow[col];
    }
    __syncthreads();
    float bv = jb.bias[t];
    float acc[8];
#pragma unroll
    for (int i = 0; i < 8; ++i) acc[i] = bv;
    for (int ic0 = 0; ic0 < 256; ic0 += 4) {
      float w[4][5];
#pragma unroll
      for (int i = 0; i < 4; ++i)
#pragma unroll
        for (int k = 0; k < 5; ++k) w[i][k] = wt[((ic0 + i) * 5 + k) * 256];
#pragma unroll
      for (int cc = 0; cc < 19; ++cc) {
        float4 xq = *(const float4*)&xs[cc * 256 + ic0];
#pragma unroll
        for (int i = 0; i < 8; ++i) {
          int k = cc - 2 * i;                 // column cc serves out i with tap k
          if (k >= 0 && k < 5)
            acc[i] += w[0][k] * xq.x + w[1][k] * xq.y + w[2][k] * xq.z + w[3][k] * xq.w;
        }
      }
    }
#pragma unroll
    for (int i = 0; i < 8; ++i) {
      int g = u0 + i;
      float vv = acc[i];
      orow[2 + g] = vv;
      if (g < 2) orow[jb.Wcore + 2 + g] = vv;
      if (g >= jb.Wcore - 2) orow[g - (jb.Wcore - 2)] = vv;
    }
  } else {
    // transposed: out[m] = sum_ic sum_{k == m mod 2} w[k] * x[((m+2-k)/2) mod Win], tile of 16 m
    int m0 = tile * 16;
    int j0 = (m0 >> 1) - 1;
#pragma unroll
    for (int cc = 0; cc < 10; ++cc) {
      int col = j0 + cc;
      col += (col < 0) ? Win : 0;
      col -= (col >= Win) ? Win : 0;
      xs[cc * 256 + t] = xrow[col];
    }
    __syncthreads();
    float acc[16];
#pragma unroll
    for (int i = 0; i < 16; ++i) acc[i] = 0.f;
    for (int ic0 = 0; ic0 < 256; ic0 += 4) {
      float w[4][5];
#pragma unroll
      for (int i = 0; i < 4; ++i)
#pragma unroll
        for (int k = 0; k < 5; ++k) w[i][k] = wt[((ic0 + i) * 5 + k) * 256];
#pragma unroll
      for (int cc = 0; cc < 10; ++cc) {
        float4 xq = *(const float4*)&xs[cc * 256 + ic0];
#pragma unroll
        for (int ml = 0; ml < 16; ++ml) {
          int k = ml + 4 - 2 * cc;            // column cc serves out ml with tap k
          if (k >= 0 && k < 5)
            acc[ml] += w[0][k] * xq.x + w[1][k] * xq.y + w[2][k] * xq.z + w[3][k] * xq.w;
        }
      }
    }
#pragma unroll
    for (int i = 0; i < 16; ++i) {
      int g = m0 + i;
      float vv = acc[i];
      orow[2 + g] = vv;
      if (g < 2) orow[jb.Wcore + 2 + g] = vv;
      if (g >= jb.Wcore - 2) orow[g - (jb.Wcore - 2)] = vv;
    }
  }
}

__device__ __forceinline__ void conv_dispatch(const MegaParams& p, int u, int t, float* xs) {
  int ji = 0;
#pragma unroll
  for (int i = 1; i < 8; ++i)
    if (u >= p.j[i].blk_start) ji = i;
  conv_block(p.j[ji], u - p.j[ji].blk_start, t, xs);
}

// --- the persistent mega kernel ---
__global__ __launch_bounds__(256, 7) void mega_kernel(MegaParams p) {
  __shared__ float xs[19 * 256];            // 19.5 KB
  int bx = blockIdx.x;
  int t = threadIdx.x;
  if (bx < 540) {
    conv_dispatch(p, bx, t, xs);            // unit bx
    __syncthreads();                        // xs reuse barrier
    conv_dispatch(p, bx + 540, t, xs);      // unit bx+540
  } else if (bx < 1410) {
    copy_strip_rows<180, 1440>(p.in2, p.o2, bx - 540, 870, t);
  } else if (bx < 1556) {
    copy_strip_rows<60, 720>(p.in1, p.o1, bx - 1410, 146, t);
  } else if (bx < 1702) {
    copy_strip_rows<60, 720>(p.in3, p.o3, bx - 1556, 146, t);
  } else if (bx < 1740) {
    copy_strip_rows<30, 360>(p.in0, p.o0, bx - 1702, 38, t);
  } else if (bx < 1778) {
    copy_strip_rows<30, 360>(p.in4, p.o4, bx - 1740, 38, t);
  } else {
    // zero rows: strip0 rows 0,1 ; strip4 rows 32,33  (1024 rows of 91 float4)
    int lb = bx - 1778;                     // 0..5
    int wave = t >> 6, lane = t & 63;
    for (int row = lb * 4 + wave; row < 1024; row += 24) {
      int strip = row >> 9;
      int cr = row & 511;
      int c = cr >> 1, r = cr & 1;
      float* dst = strip ? p.o4 + (size_t)(c * 34 + 32 + r) * 364
                         : p.o0 + (size_t)(c * 34 + r) * 364;
      for (int w4 = lane; w4 < 91; w4 += 64)
        *(float4*)(dst + w4 * 4) = make_float4(0.f, 0.f, 0.f, 0.f);
    }
  }
}

extern "C" void kernel_launch(void* const* d_in, const int* in_sizes, int n_in,
                              void* d_out, int out_size, void* d_ws, size_t ws_size,
                              hipStream_t stream) {
  const float* s0 = (const float*)d_in[0];   // (256,30,360)
  const float* s1 = (const float*)d_in[1];   // (256,60,720)
  const float* s2 = (const float*)d_in[2];   // (256,180,1440)
  const float* s3 = (const float*)d_in[3];   // (256,60,720)
  const float* s4 = (const float*)d_in[4];   // (256,30,360)
  const float* wi0 = (const float*)d_in[5];  // (256,256,1,5) [ic][oc][k]
  const float* wi1 = (const float*)d_in[6];
  const float* wo0 = (const float*)d_in[7];  // (256,256,1,5) [oc][ic][k]
  const float* bo0 = (const float*)d_in[8];
  const float* wo1 = (const float*)d_in[9];
  const float* bo1 = (const float*)d_in[10];

  float* out = (float*)d_out;
  float* out0 = out;                 // (256,34,364)
  float* out1 = out + 3168256;       // (256,64,724)
  float* out2 = out + 15030272;      // (256,184,1444)
  float* out3 = out + 83048448;      // (256,64,724)
  float* out4 = out + 94910464;      // (256,34,364)

  // transposed weights in workspace: [ic][k][oc], 327680 floats each
  float* wt0 = (float*)d_ws;
  float* wt1 = wt0 + 327680;
  float* wt2 = wt1 + 327680;
  float* wt3 = wt2 + 327680;

  WTParams wp;
  wp.src[0] = wi0; wp.src[1] = wi1; wp.src[2] = wo0; wp.src[3] = wo1;
  wp.dst[0] = wt0; wp.dst[1] = wt1; wp.dst[2] = wt2; wp.dst[3] = wt3;
  transpose_all_kernel<<<5120, 256, 0, stream>>>(wp);

  MegaParams mp;
  //           x   wt    bias    out   Hin  Win   r0  Hout Wcore h0  type blk_start
  mp.j[0] = {s1, wt0, nullptr, out2,  60,  720,  58, 184, 1440,   0, 0,   0}; // convT -> out2 top    (180 units)
  mp.j[1] = {s3, wt0, nullptr, out2,  60,  720,   0, 184, 1440, 182, 0, 180}; // convT -> out2 bottom (180)
  mp.j[2] = {s0, wt1, nullptr, out1,  30,  360,  28,  64,  720,   0, 0, 360}; // convT -> out1 top    ( 90)
  mp.j[3] = {s4, wt1, nullptr, out3,  30,  360,   0,  64,  720,  62, 0, 450}; // convT -> out3 bottom ( 90)
  mp.j[4] = {s2, wt2, bo0,     out1, 180, 1440,   0,  64,  720,  62, 1, 540}; // fwd   -> out1 bottom (180)
  mp.j[5] = {s2, wt2, bo0,     out3, 180, 1440, 178,  64,  720,   0, 1, 720}; // fwd   -> out3 top    (180)
  mp.j[6] = {s1, wt3, bo1,     out0,  60,  720,   0,  34,  360,  32, 1, 900}; // fwd   -> out0 bottom ( 90)
  mp.j[7] = {s3, wt3, bo1,     out4,  60,  720,  58,  34,  360,   0, 1, 990}; // fwd   -> out4 top    ( 90)
  mp.in0 = s0; mp.in1 = s1; mp.in2 = s2; mp.in3 = s3; mp.in4 = s4;
  mp.o0 = out0; mp.o1 = out1; mp.o2 = out2; mp.o3 = out3; mp.o4 = out4;

  mega_kernel<<<1784, 256, 0, stream>>>(mp);
}